// Round 14
// baseline (227.600 us; speedup 1.0000x reference)
//
#include <hip/hip_runtime.h>
#include <math.h>

#define NN 50000
#define FIN 128
#define EE 800000            // CSR holds only real edges; self-loops handled analytically
#define ETEST 100000
#define NEG_SLOPE 0.2f
#define NB 196               // buckets = ceil(NN/256); bucket = dst>>8
#define BB 256               // binning blocks
#define EPB 3125             // edges per binning block = EE/BB
#define BSTRIDE 5120         // per-bucket region stride (mean 4081, sd~64: 16-sigma margin)
#define XP 68                // LDS pitch for transposed x tile
#define GB1 782              // gemm1 blocks = ceil(NN/64)

static inline int cdiv(long long a, int b) { return (int)((a + b - 1) / b); }

// ---------------- CSR build: claim-based bucketed partition (no scans) ----------------

__global__ void init_gcur(int* __restrict__ gcur) {
    int t = threadIdx.x;
    if (t < NB) gcur[t] = t * BSTRIDE;
}

// ---- fused: bin (blocks 0..BB-1, latency-bound) + gemm1 (blocks BB.., compute-bound) ----
__global__ void __launch_bounds__(256) gemm1_bin_kernel(
        const float* __restrict__ x, const float* __restrict__ W,
        const float* __restrict__ att_src, const float* __restrict__ att_dst,
        float* __restrict__ h, float* __restrict__ a_src, float* __restrict__ a_dst,
        const int* __restrict__ ei, int* __restrict__ gcur, unsigned* __restrict__ binned) {
    __shared__ int hist[NB];
    __shared__ __align__(16) float Ws[FIN * 64];     // 32 KB
    __shared__ __align__(16) float xs[32 * XP];      // 8.7 KB
    int tid = threadIdx.x;
    if (blockIdx.x < BB) {
        // ---------- bin path ----------
        int blk = blockIdx.x;
        for (int b = tid; b < NB; b += 256) hist[b] = 0;
        __syncthreads();
        int beg = blk * EPB, end = beg + EPB; if (end > EE) end = EE;
        unsigned pk[13];
        int n = 0;
        for (int e = beg + tid; e < end; e += 256) {
            unsigned dst = (unsigned)ei[EE + e], src = (unsigned)ei[e];
            unsigned p = (dst << 16) | src;
            pk[n++] = p;
            atomicAdd(&hist[p >> 24], 1);
        }
        __syncthreads();
        for (int b = tid; b < NB; b += 256) {
            int c = hist[b];
            if (c > 0) hist[b] = atomicAdd(&gcur[b], c);   // claim chunk; hist becomes cursor
        }
        __syncthreads();
        for (int i = 0; i < n; ++i) {
            unsigned p = pk[i];
            int r = atomicAdd(&hist[p >> 24], 1);
            binned[r] = p;
        }
        return;
    }
    // ---------- gemm1 path ----------
    for (int i = tid; i < FIN * 64 / 4; i += 256)
        ((float4*)Ws)[i] = ((const float4*)W)[i];
    int B = (blockIdx.x - BB) * 64;
    int wave = tid >> 6, lane = tid & 63;
    int rg = lane >> 4, cg = lane & 15;
    int rbase = wave * 16 + rg * 4;
    float acc[4][4] = {};
    for (int kc = 0; kc < FIN; kc += 32) {
        __syncthreads();
#pragma unroll
        for (int p = 0; p < 2; ++p) {
            int idx = p * 256 + tid;
            int r = idx >> 3;
            int m = idx & 7;
            int row = B + r;
            float4 v = (row < NN) ? ((const float4*)(x + (size_t)row * FIN + kc))[m]
                                  : make_float4(0.f, 0.f, 0.f, 0.f);
            int c4 = m << 2;
            xs[(c4 + 0) * XP + r] = v.x;
            xs[(c4 + 1) * XP + r] = v.y;
            xs[(c4 + 2) * XP + r] = v.z;
            xs[(c4 + 3) * XP + r] = v.w;
        }
        __syncthreads();
#pragma unroll 4
        for (int k = 0; k < 32; ++k) {
            float4 w4 = *(const float4*)&Ws[(kc + k) * 64 + cg * 4];
            float4 x4 = *(const float4*)&xs[k * XP + rbase];
            acc[0][0] = fmaf(x4.x, w4.x, acc[0][0]); acc[0][1] = fmaf(x4.x, w4.y, acc[0][1]);
            acc[0][2] = fmaf(x4.x, w4.z, acc[0][2]); acc[0][3] = fmaf(x4.x, w4.w, acc[0][3]);
            acc[1][0] = fmaf(x4.y, w4.x, acc[1][0]); acc[1][1] = fmaf(x4.y, w4.y, acc[1][1]);
            acc[1][2] = fmaf(x4.y, w4.z, acc[1][2]); acc[1][3] = fmaf(x4.y, w4.w, acc[1][3]);
            acc[2][0] = fmaf(x4.z, w4.x, acc[2][0]); acc[2][1] = fmaf(x4.z, w4.y, acc[2][1]);
            acc[2][2] = fmaf(x4.z, w4.z, acc[2][2]); acc[2][3] = fmaf(x4.z, w4.w, acc[2][3]);
            acc[3][0] = fmaf(x4.w, w4.x, acc[3][0]); acc[3][1] = fmaf(x4.w, w4.y, acc[3][1]);
            acc[3][2] = fmaf(x4.w, w4.z, acc[3][2]); acc[3][3] = fmaf(x4.w, w4.w, acc[3][3]);
        }
    }
    float as0 = att_src[4 * cg + 0], as1 = att_src[4 * cg + 1],
          as2 = att_src[4 * cg + 2], as3 = att_src[4 * cg + 3];
    float ad0 = att_dst[4 * cg + 0], ad1 = att_dst[4 * cg + 1],
          ad2 = att_dst[4 * cg + 2], ad3 = att_dst[4 * cg + 3];
#pragma unroll
    for (int j = 0; j < 4; ++j) {
        int row = B + rbase + j;
        if (row >= NN) continue;
        float4 hv = make_float4(acc[j][0], acc[j][1], acc[j][2], acc[j][3]);
        *(float4*)(h + (size_t)row * 64 + cg * 4) = hv;
        float ps = fmaf(hv.x, as0, fmaf(hv.y, as1, fmaf(hv.z, as2, hv.w * as3)));
        float pd = fmaf(hv.x, ad0, fmaf(hv.y, ad1, fmaf(hv.z, ad2, hv.w * ad3)));
        ps += __shfl_xor(ps, 1, 64);
        pd += __shfl_xor(pd, 1, 64);
        if ((cg & 1) == 0) {
            a_src[row * 8 + (cg >> 1)] = ps;
            a_dst[row * 8 + (cg >> 1)] = pd;
        }
    }
}

// one block per bucket: per-node counts -> local scan -> beg/end + col (strided region)
__global__ void __launch_bounds__(256) csr_kernel(const unsigned* __restrict__ binned,
                                                  const int* __restrict__ gcur,
                                                  int* __restrict__ begA, int* __restrict__ endA,
                                                  int* __restrict__ col) {
    __shared__ int cnt[256], s[256], cur[256];
    int b = blockIdx.x, t = threadIdx.x;
    int start = b * BSTRIDE;
    int bend = gcur[b];                       // end of claimed region
    cnt[t] = 0;
    __syncthreads();
    for (int i = start + t; i < bend; i += 256)
        atomicAdd(&cnt[(binned[i] >> 16) & 255], 1);
    __syncthreads();
    int v = cnt[t];
    s[t] = v;
    __syncthreads();
#pragma unroll
    for (int o = 1; o < 256; o <<= 1) {
        int u = (t >= o) ? s[t - o] : 0;
        __syncthreads();
        s[t] += u;
        __syncthreads();
    }
    int excl = start + s[t] - v;
    int dst = b * 256 + t;
    if (dst < NN) { begA[dst] = excl; endA[dst] = excl + v; }
    cur[t] = excl;
    __syncthreads();
    for (int i = start + t; i < bend; i += 256) {
        unsigned p = binned[i];
        int dl = (p >> 16) & 255;
        int r = atomicAdd(&cur[dl], 1);
        col[r] = (int)(p & 0xFFFFu);
    }
}

// ---------------- gemm2 (64x64 tile, 4x4 acc per lane) ----------------

__global__ void __launch_bounds__(256) gemm2_kernel(
        const float* __restrict__ z, const float* __restrict__ W,
        const float* __restrict__ att_src, const float* __restrict__ att_dst,
        float* __restrict__ h, float* __restrict__ a_src, float* __restrict__ a_dst) {
    __shared__ __align__(16) float Ws[64 * 64];
    __shared__ __align__(16) float xs[64 * XP];
    int tid = threadIdx.x;
    for (int i = tid; i < 64 * 64 / 4; i += 256)
        ((float4*)Ws)[i] = ((const float4*)W)[i];
    int B = blockIdx.x * 64;
#pragma unroll
    for (int p = 0; p < 4; ++p) {
        int idx = p * 256 + tid;
        int r = idx >> 4;
        int m = idx & 15;
        int row = B + r;
        float4 v = (row < NN) ? ((const float4*)(z + (size_t)row * 64))[m]
                              : make_float4(0.f, 0.f, 0.f, 0.f);
        int c4 = m << 2;
        xs[(c4 + 0) * XP + r] = v.x;
        xs[(c4 + 1) * XP + r] = v.y;
        xs[(c4 + 2) * XP + r] = v.z;
        xs[(c4 + 3) * XP + r] = v.w;
    }
    int wave = tid >> 6, lane = tid & 63;
    int rg = lane >> 4, cg = lane & 15;
    int rbase = wave * 16 + rg * 4;
    float acc[4][4] = {};
    __syncthreads();
#pragma unroll 4
    for (int k = 0; k < 64; ++k) {
        float4 w4 = *(const float4*)&Ws[k * 64 + cg * 4];
        float4 x4 = *(const float4*)&xs[k * XP + rbase];
        acc[0][0] = fmaf(x4.x, w4.x, acc[0][0]); acc[0][1] = fmaf(x4.x, w4.y, acc[0][1]);
        acc[0][2] = fmaf(x4.x, w4.z, acc[0][2]); acc[0][3] = fmaf(x4.x, w4.w, acc[0][3]);
        acc[1][0] = fmaf(x4.y, w4.x, acc[1][0]); acc[1][1] = fmaf(x4.y, w4.y, acc[1][1]);
        acc[1][2] = fmaf(x4.y, w4.z, acc[1][2]); acc[1][3] = fmaf(x4.y, w4.w, acc[1][3]);
        acc[2][0] = fmaf(x4.z, w4.x, acc[2][0]); acc[2][1] = fmaf(x4.z, w4.y, acc[2][1]);
        acc[2][2] = fmaf(x4.z, w4.z, acc[2][2]); acc[2][3] = fmaf(x4.z, w4.w, acc[2][3]);
        acc[3][0] = fmaf(x4.w, w4.x, acc[3][0]); acc[3][1] = fmaf(x4.w, w4.y, acc[3][1]);
        acc[3][2] = fmaf(x4.w, w4.z, acc[3][2]); acc[3][3] = fmaf(x4.w, w4.w, acc[3][3]);
    }
    float as0 = att_src[4 * cg + 0], as1 = att_src[4 * cg + 1],
          as2 = att_src[4 * cg + 2], as3 = att_src[4 * cg + 3];
    float ad0 = att_dst[4 * cg + 0], ad1 = att_dst[4 * cg + 1],
          ad2 = att_dst[4 * cg + 2], ad3 = att_dst[4 * cg + 3];
#pragma unroll
    for (int j = 0; j < 4; ++j) {
        int row = B + rbase + j;
        if (row >= NN) continue;
        float4 hv = make_float4(acc[j][0], acc[j][1], acc[j][2], acc[j][3]);
        *(float4*)(h + (size_t)row * 64 + cg * 4) = hv;
        float ps = fmaf(hv.x, as0, fmaf(hv.y, as1, fmaf(hv.z, as2, hv.w * as3)));
        float pd = fmaf(hv.x, ad0, fmaf(hv.y, ad1, fmaf(hv.z, ad2, hv.w * ad3)));
#pragma unroll
        for (int off = 8; off >= 1; off >>= 1) {
            ps += __shfl_xor(ps, off, 64);
            pd += __shfl_xor(pd, off, 64);
        }
        if (cg == 0) { a_src[row] = ps; a_dst[row] = pd; }
    }
}

// ---------------- GAT aggregation: scalarized + 3-stage software pipeline ----------------
// Stage A: col load 2 chunks ahead; Stage B: asrc gather 1 chunk ahead (overlaps stage C);
// Stage C: hfeat fmas for current chunk. All pipeline branches wave-uniform.

// Layer 1: H=8, C=8. Wave per node; 8 edges/chunk.
__global__ void gat1_gather(const int* __restrict__ begA, const int* __restrict__ endA,
                            const int* __restrict__ col,
                            const float* __restrict__ asrc, const float* __restrict__ adst,
                            const float* __restrict__ hfeat, const float* __restrict__ bias,
                            float* __restrict__ z1) {
    int v = blockIdx.x * 4 + (threadIdx.x >> 6);
    if (v >= NN) return;
    int lane = threadIdx.x & 63;
    int j = lane >> 3;              // edge slot (alpha) == head (message)
    int hh = lane & 7;              // head (alpha layout)
    int beg = begA[v], end = endA[v];
    float ad_a = adst[v * 8 + hh];
    float aself = asrc[v * 8 + j] + adst[v * 8 + j];
    float eself = __expf(fmaxf(aself, NEG_SLOPE * aself));
    float acc = eself * hfeat[(size_t)v * 64 + lane];
    float den_a = 0.f;

    int vs_cur = 0, vs_nxt = 0;
    float e_cur = 0.f;
    if (beg < end) {
        int idx0 = (j < end - beg) ? beg + j : end - 1;
        vs_cur = col[idx0];
        if (beg + 8 < end) {
            int idx1 = (j < end - (beg + 8)) ? beg + 8 + j : end - 1;
            vs_nxt = col[idx1];                       // in flight for next iter
        }
        float a = asrc[vs_cur * 8 + hh] + ad_a;
        float e = __expf(fmaxf(a, NEG_SLOPE * a));
        e_cur = (j < end - beg) ? e : 0.f;
    }
    for (int i = beg; i < end; i += 8) {
        int inxt = i + 8, ifut = i + 16;
        int vs_fut = 0;
        if (ifut < end) {
            int idx = (j < end - ifut) ? ifut + j : end - 1;
            vs_fut = col[idx];                        // stage A issue
        }
        float a_nxt = 0.f;
        if (inxt < end)
            a_nxt = asrc[vs_nxt * 8 + hh] + ad_a;     // stage B issue (overlaps stage C)
        den_a += e_cur;
#pragma unroll
        for (int u = 0; u < 8; ++u) {                 // stage C
            int s_u = __builtin_amdgcn_readlane(vs_cur, u * 8);
            float eb = __shfl(e_cur, u * 8 + j, 64);
            float f = hfeat[(size_t)s_u * 64 + lane];
            acc = fmaf(eb, f, acc);
        }
        float e = __expf(fmaxf(a_nxt, NEG_SLOPE * a_nxt));
        e_cur = (inxt < end && j < end - inxt) ? e : 0.f;
        vs_cur = vs_nxt; vs_nxt = vs_fut;
    }
    den_a += __shfl_xor(den_a, 8, 64);
    den_a += __shfl_xor(den_a, 16, 64);
    den_a += __shfl_xor(den_a, 32, 64);
    float den = __shfl(den_a, j, 64) + eself;
    float o = acc / fmaxf(den, 1e-16f) + bias[lane];
    z1[(size_t)v * 64 + lane] = o > 0.f ? o : expm1f(o);   // fused ELU
}

// Layer 2: H=1, C=64; 16 edges/chunk.
__global__ void gat2_gather(const int* __restrict__ begA, const int* __restrict__ endA,
                            const int* __restrict__ col,
                            const float* __restrict__ asrc, const float* __restrict__ adst,
                            const float* __restrict__ hfeat, const float* __restrict__ bias,
                            float* __restrict__ z2) {
    int v = blockIdx.x * 4 + (threadIdx.x >> 6);
    if (v >= NN) return;
    int lane = threadIdx.x & 63;
    int j16 = lane & 15;
    int beg = begA[v], end = endA[v];
    float ad = adst[v];
    float aself = asrc[v] + ad;
    float eself = __expf(fmaxf(aself, NEG_SLOPE * aself));
    float den = eself;
    float acc = eself * hfeat[(size_t)v * 64 + lane];

    int vs_cur = 0, vs_nxt = 0;
    float e_cur = 0.f;
    if (beg < end) {
        int idx0 = (j16 < end - beg) ? beg + j16 : end - 1;
        vs_cur = col[idx0];
        if (beg + 16 < end) {
            int idx1 = (j16 < end - (beg + 16)) ? beg + 16 + j16 : end - 1;
            vs_nxt = col[idx1];
        }
        float a = asrc[vs_cur] + ad;
        float e = __expf(fmaxf(a, NEG_SLOPE * a));
        e_cur = (j16 < end - beg) ? e : 0.f;
    }
    for (int i = beg; i < end; i += 16) {
        int inxt = i + 16, ifut = i + 32;
        int vs_fut = 0;
        if (ifut < end) {
            int idx = (j16 < end - ifut) ? ifut + j16 : end - 1;
            vs_fut = col[idx];                        // stage A issue
        }
        float a_nxt = 0.f;
        if (inxt < end)
            a_nxt = asrc[vs_nxt] + ad;                // stage B issue
#pragma unroll
        for (int u = 0; u < 16; ++u) {                // stage C
            int s_u = __builtin_amdgcn_readlane(vs_cur, u);
            float e_u = __int_as_float(__builtin_amdgcn_readlane(__float_as_int(e_cur), u));
            float f = hfeat[(size_t)s_u * 64 + lane];
            den += e_u;
            acc = fmaf(e_u, f, acc);
        }
        float e = __expf(fmaxf(a_nxt, NEG_SLOPE * a_nxt));
        e_cur = (inxt < end && j16 < end - inxt) ? e : 0.f;
        vs_cur = vs_nxt; vs_nxt = vs_fut;
    }
    z2[(size_t)v * 64 + lane] = acc / fmaxf(den, 1e-16f) + bias[lane];
}

// logits[i] = dot64(z2[a], z2[b]); 16 lanes per logit, float4 loads
__global__ void logits_kernel(const int* __restrict__ pos, const int* __restrict__ neg,
                              const float* __restrict__ z2, float* __restrict__ out) {
    int t = blockIdx.x * 256 + threadIdx.x;
    int i = t >> 4;
    if (i >= 2 * ETEST) return;
    int sub = t & 15;
    int a, b;
    if (i < ETEST) { a = pos[i]; b = pos[ETEST + i]; }
    else           { a = neg[i - ETEST]; b = neg[i]; }
    float4 va = ((const float4*)(z2 + (size_t)a * 64))[sub];
    float4 vb = ((const float4*)(z2 + (size_t)b * 64))[sub];
    float p = fmaf(va.x, vb.x, fmaf(va.y, vb.y, fmaf(va.z, vb.z, va.w * vb.w)));
#pragma unroll
    for (int off = 8; off >= 1; off >>= 1) p += __shfl_xor(p, off, 64);
    if (sub == 0) out[i] = p;
}

extern "C" void kernel_launch(void* const* d_in, const int* in_sizes, int n_in,
                              void* d_out, int out_size, void* d_ws, size_t ws_size,
                              hipStream_t stream) {
    const float* x    = (const float*)d_in[0];
    const int*   ei   = (const int*)d_in[1];
    const int*   pos  = (const int*)d_in[2];
    const int*   neg  = (const int*)d_in[3];
    const float* W1   = (const float*)d_in[4];
    const float* asr1 = (const float*)d_in[5];
    const float* ads1 = (const float*)d_in[6];
    const float* b1   = (const float*)d_in[7];
    const float* W2   = (const float*)d_in[8];
    const float* asr2 = (const float*)d_in[9];
    const float* ads2 = (const float*)d_in[10];
    const float* b2   = (const float*)d_in[11];
    float* out = (float*)d_out;

    float* wsp = (float*)d_ws;
    float* h1  = wsp;                      // NN*64
    float* z1  = h1 + (size_t)NN * 64;     // NN*64
    float* z2  = z1 + (size_t)NN * 64;     // NN*64
    float* as1 = z2 + (size_t)NN * 64;     // NN*8
    float* ad1 = as1 + (size_t)NN * 8;     // NN*8
    float* as2 = ad1 + (size_t)NN * 8;     // NN
    float* ad2 = as2 + NN;                 // NN
    int* gcur   = (int*)(ad2 + NN);        // NB
    int* begA   = gcur + NB;               // NN
    int* endA   = begA + NN;               // NN
    unsigned* binned = (unsigned*)(endA + NN);        // NB*BSTRIDE
    int* csrcol = (int*)(binned + (size_t)NB * BSTRIDE); // NB*BSTRIDE

    // ---- CSR build overlapped with gemm1 ----
    init_gcur<<<1, 256, 0, stream>>>(gcur);
    gemm1_bin_kernel<<<BB + GB1, 256, 0, stream>>>(x, W1, asr1, ads1, h1, as1, ad1,
                                                   ei, gcur, binned);
    csr_kernel<<<NB, 256, 0, stream>>>(binned, gcur, begA, endA, csrcol);

    // ---- layer 1 aggregation ----
    gat1_gather<<<cdiv(NN, 4), 256, 0, stream>>>(begA, endA, csrcol, as1, ad1, h1, b1, z1);

    // ---- layer 2 ----
    gemm2_kernel<<<cdiv(NN, 64), 256, 0, stream>>>(z1, W2, asr2, ads2, h1, as2, ad2);
    gat2_gather<<<cdiv(NN, 4), 256, 0, stream>>>(begA, endA, csrcol, as2, ad2, h1, b2, z2);

    // ---- link-prediction logits ----
    logits_kernel<<<cdiv((long long)2 * ETEST * 16, 256), 256, 0, stream>>>(pos, neg, z2, out);
}

// Round 15
// 223.031 us; speedup vs baseline: 1.0205x; 1.0205x over previous
//
#include <hip/hip_runtime.h>
#include <math.h>

#define NN 50000
#define FIN 128
#define EE 800000            // CSR holds only real edges; self-loops handled analytically
#define ETEST 100000
#define NEG_SLOPE 0.2f
#define NB 196               // buckets = ceil(NN/256); bucket = dst>>8
#define BB 256               // binning blocks
#define EPB 3125             // edges per binning block = EE/BB
#define BSTRIDE 5120         // per-bucket region stride (mean 4081, sd~64: 16-sigma margin)
#define XP 68                // LDS pitch for transposed x tile
#define GB1 782              // gemm1 blocks = ceil(NN/64)

static inline int cdiv(long long a, int b) { return (int)((a + b - 1) / b); }

// ---------------- CSR build: claim-based bucketed partition (no scans) ----------------

__global__ void init_gcur(int* __restrict__ gcur) {
    int t = threadIdx.x;
    if (t < NB) gcur[t] = t * BSTRIDE;
}

// ---- fused: bin (blocks 0..BB-1, latency-bound) + gemm1 (blocks BB.., compute-bound) ----
// Independent inputs; co-scheduling hides bin's atomic/VMEM latency under gemm1 VALU work.
__global__ void __launch_bounds__(256) gemm1_bin_kernel(
        const float* __restrict__ x, const float* __restrict__ W,
        const float* __restrict__ att_src, const float* __restrict__ att_dst,
        float* __restrict__ h, float* __restrict__ a_src, float* __restrict__ a_dst,
        const int* __restrict__ ei, int* __restrict__ gcur, unsigned* __restrict__ binned) {
    __shared__ int hist[NB];
    __shared__ __align__(16) float Ws[FIN * 64];     // 32 KB
    __shared__ __align__(16) float xs[32 * XP];      // 8.7 KB
    int tid = threadIdx.x;
    if (blockIdx.x < BB) {
        // ---------- bin path ----------
        int blk = blockIdx.x;
        for (int b = tid; b < NB; b += 256) hist[b] = 0;
        __syncthreads();
        int beg = blk * EPB, end = beg + EPB; if (end > EE) end = EE;
        unsigned pk[13];
        int n = 0;
        for (int e = beg + tid; e < end; e += 256) {
            unsigned dst = (unsigned)ei[EE + e], src = (unsigned)ei[e];
            unsigned p = (dst << 16) | src;
            pk[n++] = p;
            atomicAdd(&hist[p >> 24], 1);
        }
        __syncthreads();
        for (int b = tid; b < NB; b += 256) {
            int c = hist[b];
            if (c > 0) hist[b] = atomicAdd(&gcur[b], c);   // claim chunk; hist becomes cursor
        }
        __syncthreads();
        for (int i = 0; i < n; ++i) {
            unsigned p = pk[i];
            int r = atomicAdd(&hist[p >> 24], 1);
            binned[r] = p;
        }
        return;
    }
    // ---------- gemm1 path ----------
    for (int i = tid; i < FIN * 64 / 4; i += 256)
        ((float4*)Ws)[i] = ((const float4*)W)[i];
    int B = (blockIdx.x - BB) * 64;
    int wave = tid >> 6, lane = tid & 63;
    int rg = lane >> 4, cg = lane & 15;
    int rbase = wave * 16 + rg * 4;
    float acc[4][4] = {};
    for (int kc = 0; kc < FIN; kc += 32) {
        __syncthreads();
#pragma unroll
        for (int p = 0; p < 2; ++p) {
            int idx = p * 256 + tid;
            int r = idx >> 3;
            int m = idx & 7;
            int row = B + r;
            float4 v = (row < NN) ? ((const float4*)(x + (size_t)row * FIN + kc))[m]
                                  : make_float4(0.f, 0.f, 0.f, 0.f);
            int c4 = m << 2;
            xs[(c4 + 0) * XP + r] = v.x;
            xs[(c4 + 1) * XP + r] = v.y;
            xs[(c4 + 2) * XP + r] = v.z;
            xs[(c4 + 3) * XP + r] = v.w;
        }
        __syncthreads();
#pragma unroll 4
        for (int k = 0; k < 32; ++k) {
            float4 w4 = *(const float4*)&Ws[(kc + k) * 64 + cg * 4];
            float4 x4 = *(const float4*)&xs[k * XP + rbase];
            acc[0][0] = fmaf(x4.x, w4.x, acc[0][0]); acc[0][1] = fmaf(x4.x, w4.y, acc[0][1]);
            acc[0][2] = fmaf(x4.x, w4.z, acc[0][2]); acc[0][3] = fmaf(x4.x, w4.w, acc[0][3]);
            acc[1][0] = fmaf(x4.y, w4.x, acc[1][0]); acc[1][1] = fmaf(x4.y, w4.y, acc[1][1]);
            acc[1][2] = fmaf(x4.y, w4.z, acc[1][2]); acc[1][3] = fmaf(x4.y, w4.w, acc[1][3]);
            acc[2][0] = fmaf(x4.z, w4.x, acc[2][0]); acc[2][1] = fmaf(x4.z, w4.y, acc[2][1]);
            acc[2][2] = fmaf(x4.z, w4.z, acc[2][2]); acc[2][3] = fmaf(x4.z, w4.w, acc[2][3]);
            acc[3][0] = fmaf(x4.w, w4.x, acc[3][0]); acc[3][1] = fmaf(x4.w, w4.y, acc[3][1]);
            acc[3][2] = fmaf(x4.w, w4.z, acc[3][2]); acc[3][3] = fmaf(x4.w, w4.w, acc[3][3]);
        }
    }
    float as0 = att_src[4 * cg + 0], as1 = att_src[4 * cg + 1],
          as2 = att_src[4 * cg + 2], as3 = att_src[4 * cg + 3];
    float ad0 = att_dst[4 * cg + 0], ad1 = att_dst[4 * cg + 1],
          ad2 = att_dst[4 * cg + 2], ad3 = att_dst[4 * cg + 3];
#pragma unroll
    for (int j = 0; j < 4; ++j) {
        int row = B + rbase + j;
        if (row >= NN) continue;
        float4 hv = make_float4(acc[j][0], acc[j][1], acc[j][2], acc[j][3]);
        *(float4*)(h + (size_t)row * 64 + cg * 4) = hv;
        float ps = fmaf(hv.x, as0, fmaf(hv.y, as1, fmaf(hv.z, as2, hv.w * as3)));
        float pd = fmaf(hv.x, ad0, fmaf(hv.y, ad1, fmaf(hv.z, ad2, hv.w * ad3)));
        ps += __shfl_xor(ps, 1, 64);
        pd += __shfl_xor(pd, 1, 64);
        if ((cg & 1) == 0) {
            a_src[row * 8 + (cg >> 1)] = ps;
            a_dst[row * 8 + (cg >> 1)] = pd;
        }
    }
}

// one block per bucket: per-node counts -> local scan -> beg/end + col (strided region)
__global__ void __launch_bounds__(256) csr_kernel(const unsigned* __restrict__ binned,
                                                  const int* __restrict__ gcur,
                                                  int* __restrict__ begA, int* __restrict__ endA,
                                                  int* __restrict__ col) {
    __shared__ int cnt[256], s[256], cur[256];
    int b = blockIdx.x, t = threadIdx.x;
    int start = b * BSTRIDE;
    int bend = gcur[b];                       // end of claimed region
    cnt[t] = 0;
    __syncthreads();
    for (int i = start + t; i < bend; i += 256)
        atomicAdd(&cnt[(binned[i] >> 16) & 255], 1);
    __syncthreads();
    int v = cnt[t];
    s[t] = v;
    __syncthreads();
#pragma unroll
    for (int o = 1; o < 256; o <<= 1) {
        int u = (t >= o) ? s[t - o] : 0;
        __syncthreads();
        s[t] += u;
        __syncthreads();
    }
    int excl = start + s[t] - v;
    int dst = b * 256 + t;
    if (dst < NN) { begA[dst] = excl; endA[dst] = excl + v; }
    cur[t] = excl;
    __syncthreads();
    for (int i = start + t; i < bend; i += 256) {
        unsigned p = binned[i];
        int dl = (p >> 16) & 255;
        int r = atomicAdd(&cur[dl], 1);
        col[r] = (int)(p & 0xFFFFu);
    }
}

// ---------------- gemm2 (64x64 tile, 4x4 acc per lane) ----------------

__global__ void __launch_bounds__(256) gemm2_kernel(
        const float* __restrict__ z, const float* __restrict__ W,
        const float* __restrict__ att_src, const float* __restrict__ att_dst,
        float* __restrict__ h, float* __restrict__ a_src, float* __restrict__ a_dst) {
    __shared__ __align__(16) float Ws[64 * 64];
    __shared__ __align__(16) float xs[64 * XP];
    int tid = threadIdx.x;
    for (int i = tid; i < 64 * 64 / 4; i += 256)
        ((float4*)Ws)[i] = ((const float4*)W)[i];
    int B = blockIdx.x * 64;
#pragma unroll
    for (int p = 0; p < 4; ++p) {
        int idx = p * 256 + tid;
        int r = idx >> 4;
        int m = idx & 15;
        int row = B + r;
        float4 v = (row < NN) ? ((const float4*)(z + (size_t)row * 64))[m]
                              : make_float4(0.f, 0.f, 0.f, 0.f);
        int c4 = m << 2;
        xs[(c4 + 0) * XP + r] = v.x;
        xs[(c4 + 1) * XP + r] = v.y;
        xs[(c4 + 2) * XP + r] = v.z;
        xs[(c4 + 3) * XP + r] = v.w;
    }
    int wave = tid >> 6, lane = tid & 63;
    int rg = lane >> 4, cg = lane & 15;
    int rbase = wave * 16 + rg * 4;
    float acc[4][4] = {};
    __syncthreads();
#pragma unroll 4
    for (int k = 0; k < 64; ++k) {
        float4 w4 = *(const float4*)&Ws[k * 64 + cg * 4];
        float4 x4 = *(const float4*)&xs[k * XP + rbase];
        acc[0][0] = fmaf(x4.x, w4.x, acc[0][0]); acc[0][1] = fmaf(x4.x, w4.y, acc[0][1]);
        acc[0][2] = fmaf(x4.x, w4.z, acc[0][2]); acc[0][3] = fmaf(x4.x, w4.w, acc[0][3]);
        acc[1][0] = fmaf(x4.y, w4.x, acc[1][0]); acc[1][1] = fmaf(x4.y, w4.y, acc[1][1]);
        acc[1][2] = fmaf(x4.y, w4.z, acc[1][2]); acc[1][3] = fmaf(x4.y, w4.w, acc[1][3]);
        acc[2][0] = fmaf(x4.z, w4.x, acc[2][0]); acc[2][1] = fmaf(x4.z, w4.y, acc[2][1]);
        acc[2][2] = fmaf(x4.z, w4.z, acc[2][2]); acc[2][3] = fmaf(x4.z, w4.w, acc[2][3]);
        acc[3][0] = fmaf(x4.w, w4.x, acc[3][0]); acc[3][1] = fmaf(x4.w, w4.y, acc[3][1]);
        acc[3][2] = fmaf(x4.w, w4.z, acc[3][2]); acc[3][3] = fmaf(x4.w, w4.w, acc[3][3]);
    }
    float as0 = att_src[4 * cg + 0], as1 = att_src[4 * cg + 1],
          as2 = att_src[4 * cg + 2], as3 = att_src[4 * cg + 3];
    float ad0 = att_dst[4 * cg + 0], ad1 = att_dst[4 * cg + 1],
          ad2 = att_dst[4 * cg + 2], ad3 = att_dst[4 * cg + 3];
#pragma unroll
    for (int j = 0; j < 4; ++j) {
        int row = B + rbase + j;
        if (row >= NN) continue;
        float4 hv = make_float4(acc[j][0], acc[j][1], acc[j][2], acc[j][3]);
        *(float4*)(h + (size_t)row * 64 + cg * 4) = hv;
        float ps = fmaf(hv.x, as0, fmaf(hv.y, as1, fmaf(hv.z, as2, hv.w * as3)));
        float pd = fmaf(hv.x, ad0, fmaf(hv.y, ad1, fmaf(hv.z, ad2, hv.w * ad3)));
#pragma unroll
        for (int off = 8; off >= 1; off >>= 1) {
            ps += __shfl_xor(ps, off, 64);
            pd += __shfl_xor(pd, off, 64);
        }
        if (cg == 0) { a_src[row] = ps; a_dst[row] = pd; }
    }
}

// ---------------- Fused GAT aggregation: scalarized edge loop (R7/R12 form) ----------------

// Layer 1: H=8, C=8. Wave per node. 8 edges/chunk; phase 2 via readlane saddr loads.
__global__ void gat1_gather(const int* __restrict__ begA, const int* __restrict__ endA,
                            const int* __restrict__ col,
                            const float* __restrict__ asrc, const float* __restrict__ adst,
                            const float* __restrict__ hfeat, const float* __restrict__ bias,
                            float* __restrict__ z1) {
    int v = blockIdx.x * 4 + (threadIdx.x >> 6);
    if (v >= NN) return;
    int lane = threadIdx.x & 63;
    int j = lane >> 3;              // edge slot (alpha) == head (message)
    int hh = lane & 7;              // head (alpha layout)
    int beg = begA[v], end = endA[v];
    float ad_a = adst[v * 8 + hh];
    float aself = asrc[v * 8 + j] + adst[v * 8 + j];
    float eself = __expf(fmaxf(aself, NEG_SLOPE * aself));
    float acc = eself * hfeat[(size_t)v * 64 + lane];
    float den_a = 0.f;
    for (int i = beg; i < end; i += 8) {
        int lim = end - i;
        int idx = (j < lim) ? i + j : end - 1;
        int vs = col[idx];
        float a = asrc[vs * 8 + hh] + ad_a;
        float e = __expf(fmaxf(a, NEG_SLOPE * a));
        e = (j < lim) ? e : 0.f;
        den_a += e;
#pragma unroll
        for (int u = 0; u < 8; ++u) {
            int s_u = __builtin_amdgcn_readlane(vs, u * 8);
            float eb = __shfl(e, u * 8 + j, 64);
            float f = hfeat[(size_t)s_u * 64 + lane];
            acc = fmaf(eb, f, acc);
        }
    }
    den_a += __shfl_xor(den_a, 8, 64);
    den_a += __shfl_xor(den_a, 16, 64);
    den_a += __shfl_xor(den_a, 32, 64);
    float den = __shfl(den_a, j, 64) + eself;
    float o = acc / fmaxf(den, 1e-16f) + bias[lane];
    z1[(size_t)v * 64 + lane] = o > 0.f ? o : expm1f(o);   // fused ELU
}

// Layer 2: H=1, C=64. 16 edges/chunk; scalar e + saddr row loads.
__global__ void gat2_gather(const int* __restrict__ begA, const int* __restrict__ endA,
                            const int* __restrict__ col,
                            const float* __restrict__ asrc, const float* __restrict__ adst,
                            const float* __restrict__ hfeat, const float* __restrict__ bias,
                            float* __restrict__ z2) {
    int v = blockIdx.x * 4 + (threadIdx.x >> 6);
    if (v >= NN) return;
    int lane = threadIdx.x & 63;
    int j16 = lane & 15;
    int beg = begA[v], end = endA[v];
    float ad = adst[v];
    float aself = asrc[v] + ad;
    float eself = __expf(fmaxf(aself, NEG_SLOPE * aself));
    float den = eself;
    float acc = eself * hfeat[(size_t)v * 64 + lane];
    for (int i = beg; i < end; i += 16) {
        int lim = end - i;
        int idx = (j16 < lim) ? i + j16 : end - 1;
        int vs = col[idx];
        float a = asrc[vs] + ad;
        float e = __expf(fmaxf(a, NEG_SLOPE * a));
        e = (j16 < lim) ? e : 0.f;
#pragma unroll
        for (int u = 0; u < 16; ++u) {
            int s_u = __builtin_amdgcn_readlane(vs, u);
            float e_u = __int_as_float(__builtin_amdgcn_readlane(__float_as_int(e), u));
            float f = hfeat[(size_t)s_u * 64 + lane];
            den += e_u;
            acc = fmaf(e_u, f, acc);
        }
    }
    z2[(size_t)v * 64 + lane] = acc / fmaxf(den, 1e-16f) + bias[lane];
}

// logits[i] = dot64(z2[a], z2[b]); 8 lanes per logit, 2x float4 per row per lane
// (8 logits/wave -> 32 independent 16B loads in flight; 3-step reduction)
__global__ void logits_kernel(const int* __restrict__ pos, const int* __restrict__ neg,
                              const float* __restrict__ z2, float* __restrict__ out) {
    int t = blockIdx.x * 256 + threadIdx.x;
    int i = t >> 3;
    if (i >= 2 * ETEST) return;
    int sub = t & 7;
    int a, b;
    if (i < ETEST) { a = pos[i]; b = pos[ETEST + i]; }
    else           { a = neg[i - ETEST]; b = neg[i]; }
    const float4* pa = (const float4*)(z2 + (size_t)a * 64) + sub * 2;
    const float4* pb = (const float4*)(z2 + (size_t)b * 64) + sub * 2;
    float4 va0 = pa[0], va1 = pa[1];
    float4 vb0 = pb[0], vb1 = pb[1];
    float p = fmaf(va0.x, vb0.x, fmaf(va0.y, vb0.y, fmaf(va0.z, vb0.z, va0.w * vb0.w)));
    p = fmaf(va1.x, vb1.x, fmaf(va1.y, vb1.y, fmaf(va1.z, vb1.z, fmaf(va1.w, vb1.w, p))));
#pragma unroll
    for (int off = 4; off >= 1; off >>= 1) p += __shfl_xor(p, off, 64);
    if (sub == 0) out[i] = p;
}

extern "C" void kernel_launch(void* const* d_in, const int* in_sizes, int n_in,
                              void* d_out, int out_size, void* d_ws, size_t ws_size,
                              hipStream_t stream) {
    const float* x    = (const float*)d_in[0];
    const int*   ei   = (const int*)d_in[1];
    const int*   pos  = (const int*)d_in[2];
    const int*   neg  = (const int*)d_in[3];
    const float* W1   = (const float*)d_in[4];
    const float* asr1 = (const float*)d_in[5];
    const float* ads1 = (const float*)d_in[6];
    const float* b1   = (const float*)d_in[7];
    const float* W2   = (const float*)d_in[8];
    const float* asr2 = (const float*)d_in[9];
    const float* ads2 = (const float*)d_in[10];
    const float* b2   = (const float*)d_in[11];
    float* out = (float*)d_out;

    float* wsp = (float*)d_ws;
    float* h1  = wsp;                      // NN*64
    float* z1  = h1 + (size_t)NN * 64;     // NN*64
    float* z2  = z1 + (size_t)NN * 64;     // NN*64
    float* as1 = z2 + (size_t)NN * 64;     // NN*8
    float* ad1 = as1 + (size_t)NN * 8;     // NN*8
    float* as2 = ad1 + (size_t)NN * 8;     // NN
    float* ad2 = as2 + NN;                 // NN
    int* gcur   = (int*)(ad2 + NN);        // NB
    int* begA   = gcur + NB;               // NN
    int* endA   = begA + NN;               // NN
    unsigned* binned = (unsigned*)(endA + NN);        // NB*BSTRIDE
    int* csrcol = (int*)(binned + (size_t)NB * BSTRIDE); // NB*BSTRIDE

    // ---- CSR build overlapped with gemm1 ----
    init_gcur<<<1, 256, 0, stream>>>(gcur);
    gemm1_bin_kernel<<<BB + GB1, 256, 0, stream>>>(x, W1, asr1, ads1, h1, as1, ad1,
                                                   ei, gcur, binned);
    csr_kernel<<<NB, 256, 0, stream>>>(binned, gcur, begA, endA, csrcol);

    // ---- layer 1 aggregation ----
    gat1_gather<<<cdiv(NN, 4), 256, 0, stream>>>(begA, endA, csrcol, as1, ad1, h1, b1, z1);

    // ---- layer 2 ----
    gemm2_kernel<<<cdiv(NN, 64), 256, 0, stream>>>(z1, W2, asr2, ads2, h1, as2, ad2);
    gat2_gather<<<cdiv(NN, 4), 256, 0, stream>>>(begA, endA, csrcol, as2, ad2, h1, b2, z2);

    // ---- link-prediction logits ----
    logits_kernel<<<cdiv((long long)2 * ETEST * 8, 256), 256, 0, stream>>>(pos, neg, z2, out);
}

// Round 16
// 220.774 us; speedup vs baseline: 1.0309x; 1.0102x over previous
//
#include <hip/hip_runtime.h>
#include <math.h>

#define NN 50000
#define FIN 128
#define EE 800000            // CSR holds only real edges; self-loops handled analytically
#define ETEST 100000
#define NEG_SLOPE 0.2f
#define NB 196               // buckets = ceil(NN/256); bucket = dst>>8
#define BB 256               // binning blocks
#define EPB 3125             // edges per binning block = EE/BB
#define BSTRIDE 5120         // per-bucket region stride (mean 4081, sd~64: 16-sigma margin)
#define XP 68                // LDS pitch for transposed x tile
#define GB1 782              // gemm1 blocks = ceil(NN/64)

static inline int cdiv(long long a, int b) { return (int)((a + b - 1) / b); }

// ---------------- CSR build: claim-based bucketed partition (no scans) ----------------

__global__ void init_gcur(int* __restrict__ gcur) {
    int t = threadIdx.x;
    if (t < NB) gcur[t] = t * BSTRIDE;
}

// ---- fused: bin (blocks 0..BB-1, latency-bound) + gemm1 (blocks BB.., compute-bound) ----
// Independent inputs; co-scheduling hides bin's atomic/VMEM latency under gemm1 VALU work.
__global__ void __launch_bounds__(256) gemm1_bin_kernel(
        const float* __restrict__ x, const float* __restrict__ W,
        const float* __restrict__ att_src, const float* __restrict__ att_dst,
        float* __restrict__ h, float* __restrict__ a_src, float* __restrict__ a_dst,
        const int* __restrict__ ei, int* __restrict__ gcur, unsigned* __restrict__ binned) {
    __shared__ int hist[NB];
    __shared__ __align__(16) float Ws[FIN * 64];     // 32 KB
    __shared__ __align__(16) float xs[32 * XP];      // 8.7 KB
    int tid = threadIdx.x;
    if (blockIdx.x < BB) {
        // ---------- bin path ----------
        int blk = blockIdx.x;
        for (int b = tid; b < NB; b += 256) hist[b] = 0;
        __syncthreads();
        int beg = blk * EPB, end = beg + EPB; if (end > EE) end = EE;
        unsigned pk[13];
        int n = 0;
        for (int e = beg + tid; e < end; e += 256) {
            unsigned dst = (unsigned)ei[EE + e], src = (unsigned)ei[e];
            unsigned p = (dst << 16) | src;
            pk[n++] = p;
            atomicAdd(&hist[p >> 24], 1);
        }
        __syncthreads();
        for (int b = tid; b < NB; b += 256) {
            int c = hist[b];
            if (c > 0) hist[b] = atomicAdd(&gcur[b], c);   // claim chunk; hist becomes cursor
        }
        __syncthreads();
        for (int i = 0; i < n; ++i) {
            unsigned p = pk[i];
            int r = atomicAdd(&hist[p >> 24], 1);
            binned[r] = p;
        }
        return;
    }
    // ---------- gemm1 path ----------
    for (int i = tid; i < FIN * 64 / 4; i += 256)
        ((float4*)Ws)[i] = ((const float4*)W)[i];
    int B = (blockIdx.x - BB) * 64;
    int wave = tid >> 6, lane = tid & 63;
    int rg = lane >> 4, cg = lane & 15;
    int rbase = wave * 16 + rg * 4;
    float acc[4][4] = {};
    for (int kc = 0; kc < FIN; kc += 32) {
        __syncthreads();
#pragma unroll
        for (int p = 0; p < 2; ++p) {
            int idx = p * 256 + tid;
            int r = idx >> 3;
            int m = idx & 7;
            int row = B + r;
            float4 v = (row < NN) ? ((const float4*)(x + (size_t)row * FIN + kc))[m]
                                  : make_float4(0.f, 0.f, 0.f, 0.f);
            int c4 = m << 2;
            xs[(c4 + 0) * XP + r] = v.x;
            xs[(c4 + 1) * XP + r] = v.y;
            xs[(c4 + 2) * XP + r] = v.z;
            xs[(c4 + 3) * XP + r] = v.w;
        }
        __syncthreads();
#pragma unroll 4
        for (int k = 0; k < 32; ++k) {
            float4 w4 = *(const float4*)&Ws[(kc + k) * 64 + cg * 4];
            float4 x4 = *(const float4*)&xs[k * XP + rbase];
            acc[0][0] = fmaf(x4.x, w4.x, acc[0][0]); acc[0][1] = fmaf(x4.x, w4.y, acc[0][1]);
            acc[0][2] = fmaf(x4.x, w4.z, acc[0][2]); acc[0][3] = fmaf(x4.x, w4.w, acc[0][3]);
            acc[1][0] = fmaf(x4.y, w4.x, acc[1][0]); acc[1][1] = fmaf(x4.y, w4.y, acc[1][1]);
            acc[1][2] = fmaf(x4.y, w4.z, acc[1][2]); acc[1][3] = fmaf(x4.y, w4.w, acc[1][3]);
            acc[2][0] = fmaf(x4.z, w4.x, acc[2][0]); acc[2][1] = fmaf(x4.z, w4.y, acc[2][1]);
            acc[2][2] = fmaf(x4.z, w4.z, acc[2][2]); acc[2][3] = fmaf(x4.z, w4.w, acc[2][3]);
            acc[3][0] = fmaf(x4.w, w4.x, acc[3][0]); acc[3][1] = fmaf(x4.w, w4.y, acc[3][1]);
            acc[3][2] = fmaf(x4.w, w4.z, acc[3][2]); acc[3][3] = fmaf(x4.w, w4.w, acc[3][3]);
        }
    }
    float as0 = att_src[4 * cg + 0], as1 = att_src[4 * cg + 1],
          as2 = att_src[4 * cg + 2], as3 = att_src[4 * cg + 3];
    float ad0 = att_dst[4 * cg + 0], ad1 = att_dst[4 * cg + 1],
          ad2 = att_dst[4 * cg + 2], ad3 = att_dst[4 * cg + 3];
#pragma unroll
    for (int j = 0; j < 4; ++j) {
        int row = B + rbase + j;
        if (row >= NN) continue;
        float4 hv = make_float4(acc[j][0], acc[j][1], acc[j][2], acc[j][3]);
        *(float4*)(h + (size_t)row * 64 + cg * 4) = hv;
        float ps = fmaf(hv.x, as0, fmaf(hv.y, as1, fmaf(hv.z, as2, hv.w * as3)));
        float pd = fmaf(hv.x, ad0, fmaf(hv.y, ad1, fmaf(hv.z, ad2, hv.w * ad3)));
        ps += __shfl_xor(ps, 1, 64);
        pd += __shfl_xor(pd, 1, 64);
        if ((cg & 1) == 0) {
            a_src[row * 8 + (cg >> 1)] = ps;
            a_dst[row * 8 + (cg >> 1)] = pd;
        }
    }
}

// one block per bucket: per-node counts -> local scan -> beg/end + col (strided region)
__global__ void __launch_bounds__(256) csr_kernel(const unsigned* __restrict__ binned,
                                                  const int* __restrict__ gcur,
                                                  int* __restrict__ begA, int* __restrict__ endA,
                                                  int* __restrict__ col) {
    __shared__ int cnt[256], s[256], cur[256];
    int b = blockIdx.x, t = threadIdx.x;
    int start = b * BSTRIDE;
    int bend = gcur[b];                       // end of claimed region
    cnt[t] = 0;
    __syncthreads();
    for (int i = start + t; i < bend; i += 256)
        atomicAdd(&cnt[(binned[i] >> 16) & 255], 1);
    __syncthreads();
    int v = cnt[t];
    s[t] = v;
    __syncthreads();
#pragma unroll
    for (int o = 1; o < 256; o <<= 1) {
        int u = (t >= o) ? s[t - o] : 0;
        __syncthreads();
        s[t] += u;
        __syncthreads();
    }
    int excl = start + s[t] - v;
    int dst = b * 256 + t;
    if (dst < NN) { begA[dst] = excl; endA[dst] = excl + v; }
    cur[t] = excl;
    __syncthreads();
    for (int i = start + t; i < bend; i += 256) {
        unsigned p = binned[i];
        int dl = (p >> 16) & 255;
        int r = atomicAdd(&cur[dl], 1);
        col[r] = (int)(p & 0xFFFFu);
    }
}

// ---------------- gemm2 (64x64 tile, 4x4 acc per lane) ----------------

__global__ void __launch_bounds__(256) gemm2_kernel(
        const float* __restrict__ z, const float* __restrict__ W,
        const float* __restrict__ att_src, const float* __restrict__ att_dst,
        float* __restrict__ h, float* __restrict__ a_src, float* __restrict__ a_dst) {
    __shared__ __align__(16) float Ws[64 * 64];
    __shared__ __align__(16) float xs[64 * XP];
    int tid = threadIdx.x;
    for (int i = tid; i < 64 * 64 / 4; i += 256)
        ((float4*)Ws)[i] = ((const float4*)W)[i];
    int B = blockIdx.x * 64;
#pragma unroll
    for (int p = 0; p < 4; ++p) {
        int idx = p * 256 + tid;
        int r = idx >> 4;
        int m = idx & 15;
        int row = B + r;
        float4 v = (row < NN) ? ((const float4*)(z + (size_t)row * 64))[m]
                              : make_float4(0.f, 0.f, 0.f, 0.f);
        int c4 = m << 2;
        xs[(c4 + 0) * XP + r] = v.x;
        xs[(c4 + 1) * XP + r] = v.y;
        xs[(c4 + 2) * XP + r] = v.z;
        xs[(c4 + 3) * XP + r] = v.w;
    }
    int wave = tid >> 6, lane = tid & 63;
    int rg = lane >> 4, cg = lane & 15;
    int rbase = wave * 16 + rg * 4;
    float acc[4][4] = {};
    __syncthreads();
#pragma unroll 4
    for (int k = 0; k < 64; ++k) {
        float4 w4 = *(const float4*)&Ws[k * 64 + cg * 4];
        float4 x4 = *(const float4*)&xs[k * XP + rbase];
        acc[0][0] = fmaf(x4.x, w4.x, acc[0][0]); acc[0][1] = fmaf(x4.x, w4.y, acc[0][1]);
        acc[0][2] = fmaf(x4.x, w4.z, acc[0][2]); acc[0][3] = fmaf(x4.x, w4.w, acc[0][3]);
        acc[1][0] = fmaf(x4.y, w4.x, acc[1][0]); acc[1][1] = fmaf(x4.y, w4.y, acc[1][1]);
        acc[1][2] = fmaf(x4.y, w4.z, acc[1][2]); acc[1][3] = fmaf(x4.y, w4.w, acc[1][3]);
        acc[2][0] = fmaf(x4.z, w4.x, acc[2][0]); acc[2][1] = fmaf(x4.z, w4.y, acc[2][1]);
        acc[2][2] = fmaf(x4.z, w4.z, acc[2][2]); acc[2][3] = fmaf(x4.z, w4.w, acc[2][3]);
        acc[3][0] = fmaf(x4.w, w4.x, acc[3][0]); acc[3][1] = fmaf(x4.w, w4.y, acc[3][1]);
        acc[3][2] = fmaf(x4.w, w4.z, acc[3][2]); acc[3][3] = fmaf(x4.w, w4.w, acc[3][3]);
    }
    float as0 = att_src[4 * cg + 0], as1 = att_src[4 * cg + 1],
          as2 = att_src[4 * cg + 2], as3 = att_src[4 * cg + 3];
    float ad0 = att_dst[4 * cg + 0], ad1 = att_dst[4 * cg + 1],
          ad2 = att_dst[4 * cg + 2], ad3 = att_dst[4 * cg + 3];
#pragma unroll
    for (int j = 0; j < 4; ++j) {
        int row = B + rbase + j;
        if (row >= NN) continue;
        float4 hv = make_float4(acc[j][0], acc[j][1], acc[j][2], acc[j][3]);
        *(float4*)(h + (size_t)row * 64 + cg * 4) = hv;
        float ps = fmaf(hv.x, as0, fmaf(hv.y, as1, fmaf(hv.z, as2, hv.w * as3)));
        float pd = fmaf(hv.x, ad0, fmaf(hv.y, ad1, fmaf(hv.z, ad2, hv.w * ad3)));
#pragma unroll
        for (int off = 8; off >= 1; off >>= 1) {
            ps += __shfl_xor(ps, off, 64);
            pd += __shfl_xor(pd, off, 64);
        }
        if (cg == 0) { a_src[row] = ps; a_dst[row] = pd; }
    }
}

// ---------------- Fused GAT aggregation: scalarized edge loop (R7/R12 form) ----------------

// Layer 1: H=8, C=8. Wave per node. 8 edges/chunk; phase 2 via readlane saddr loads.
__global__ void gat1_gather(const int* __restrict__ begA, const int* __restrict__ endA,
                            const int* __restrict__ col,
                            const float* __restrict__ asrc, const float* __restrict__ adst,
                            const float* __restrict__ hfeat, const float* __restrict__ bias,
                            float* __restrict__ z1) {
    int v = blockIdx.x * 4 + (threadIdx.x >> 6);
    if (v >= NN) return;
    int lane = threadIdx.x & 63;
    int j = lane >> 3;              // edge slot (alpha) == head (message)
    int hh = lane & 7;              // head (alpha layout)
    int beg = begA[v], end = endA[v];
    float ad_a = adst[v * 8 + hh];
    float aself = asrc[v * 8 + j] + adst[v * 8 + j];
    float eself = __expf(fmaxf(aself, NEG_SLOPE * aself));
    float acc = eself * hfeat[(size_t)v * 64 + lane];
    float den_a = 0.f;
    for (int i = beg; i < end; i += 8) {
        int lim = end - i;
        int idx = (j < lim) ? i + j : end - 1;
        int vs = col[idx];
        float a = asrc[vs * 8 + hh] + ad_a;
        float e = __expf(fmaxf(a, NEG_SLOPE * a));
        e = (j < lim) ? e : 0.f;
        den_a += e;
#pragma unroll
        for (int u = 0; u < 8; ++u) {
            int s_u = __builtin_amdgcn_readlane(vs, u * 8);
            float eb = __shfl(e, u * 8 + j, 64);
            float f = hfeat[(size_t)s_u * 64 + lane];
            acc = fmaf(eb, f, acc);
        }
    }
    den_a += __shfl_xor(den_a, 8, 64);
    den_a += __shfl_xor(den_a, 16, 64);
    den_a += __shfl_xor(den_a, 32, 64);
    float den = __shfl(den_a, j, 64) + eself;
    float o = acc / fmaxf(den, 1e-16f) + bias[lane];
    z1[(size_t)v * 64 + lane] = o > 0.f ? o : expm1f(o);   // fused ELU
}

// Layer 2: H=1, C=64. 16 edges/chunk; scalar e + saddr row loads.
__global__ void gat2_gather(const int* __restrict__ begA, const int* __restrict__ endA,
                            const int* __restrict__ col,
                            const float* __restrict__ asrc, const float* __restrict__ adst,
                            const float* __restrict__ hfeat, const float* __restrict__ bias,
                            float* __restrict__ z2) {
    int v = blockIdx.x * 4 + (threadIdx.x >> 6);
    if (v >= NN) return;
    int lane = threadIdx.x & 63;
    int j16 = lane & 15;
    int beg = begA[v], end = endA[v];
    float ad = adst[v];
    float aself = asrc[v] + ad;
    float eself = __expf(fmaxf(aself, NEG_SLOPE * aself));
    float den = eself;
    float acc = eself * hfeat[(size_t)v * 64 + lane];
    for (int i = beg; i < end; i += 16) {
        int lim = end - i;
        int idx = (j16 < lim) ? i + j16 : end - 1;
        int vs = col[idx];
        float a = asrc[vs] + ad;
        float e = __expf(fmaxf(a, NEG_SLOPE * a));
        e = (j16 < lim) ? e : 0.f;
#pragma unroll
        for (int u = 0; u < 16; ++u) {
            int s_u = __builtin_amdgcn_readlane(vs, u);
            float e_u = __int_as_float(__builtin_amdgcn_readlane(__float_as_int(e), u));
            float f = hfeat[(size_t)s_u * 64 + lane];
            den += e_u;
            acc = fmaf(e_u, f, acc);
        }
    }
    z2[(size_t)v * 64 + lane] = acc / fmaxf(den, 1e-16f) + bias[lane];
}

// logits[i] = dot64(z2[a], z2[b]); 16 lanes per logit, float4 loads
__global__ void logits_kernel(const int* __restrict__ pos, const int* __restrict__ neg,
                              const float* __restrict__ z2, float* __restrict__ out) {
    int t = blockIdx.x * 256 + threadIdx.x;
    int i = t >> 4;
    if (i >= 2 * ETEST) return;
    int sub = t & 15;
    int a, b;
    if (i < ETEST) { a = pos[i]; b = pos[ETEST + i]; }
    else           { a = neg[i - ETEST]; b = neg[i]; }
    float4 va = ((const float4*)(z2 + (size_t)a * 64))[sub];
    float4 vb = ((const float4*)(z2 + (size_t)b * 64))[sub];
    float p = fmaf(va.x, vb.x, fmaf(va.y, vb.y, fmaf(va.z, vb.z, va.w * vb.w)));
#pragma unroll
    for (int off = 8; off >= 1; off >>= 1) p += __shfl_xor(p, off, 64);
    if (sub == 0) out[i] = p;
}

extern "C" void kernel_launch(void* const* d_in, const int* in_sizes, int n_in,
                              void* d_out, int out_size, void* d_ws, size_t ws_size,
                              hipStream_t stream) {
    const float* x    = (const float*)d_in[0];
    const int*   ei   = (const int*)d_in[1];
    const int*   pos  = (const int*)d_in[2];
    const int*   neg  = (const int*)d_in[3];
    const float* W1   = (const float*)d_in[4];
    const float* asr1 = (const float*)d_in[5];
    const float* ads1 = (const float*)d_in[6];
    const float* b1   = (const float*)d_in[7];
    const float* W2   = (const float*)d_in[8];
    const float* asr2 = (const float*)d_in[9];
    const float* ads2 = (const float*)d_in[10];
    const float* b2   = (const float*)d_in[11];
    float* out = (float*)d_out;

    float* wsp = (float*)d_ws;
    float* h1  = wsp;                      // NN*64
    float* z1  = h1 + (size_t)NN * 64;     // NN*64
    float* z2  = z1 + (size_t)NN * 64;     // NN*64
    float* as1 = z2 + (size_t)NN * 64;     // NN*8
    float* ad1 = as1 + (size_t)NN * 8;     // NN*8
    float* as2 = ad1 + (size_t)NN * 8;     // NN
    float* ad2 = as2 + NN;                 // NN
    int* gcur   = (int*)(ad2 + NN);        // NB
    int* begA   = gcur + NB;               // NN
    int* endA   = begA + NN;               // NN
    unsigned* binned = (unsigned*)(endA + NN);        // NB*BSTRIDE
    int* csrcol = (int*)(binned + (size_t)NB * BSTRIDE); // NB*BSTRIDE

    // ---- CSR build overlapped with gemm1 ----
    init_gcur<<<1, 256, 0, stream>>>(gcur);
    gemm1_bin_kernel<<<BB + GB1, 256, 0, stream>>>(x, W1, asr1, ads1, h1, as1, ad1,
                                                   ei, gcur, binned);
    csr_kernel<<<NB, 256, 0, stream>>>(binned, gcur, begA, endA, csrcol);

    // ---- layer 1 aggregation ----
    gat1_gather<<<cdiv(NN, 4), 256, 0, stream>>>(begA, endA, csrcol, as1, ad1, h1, b1, z1);

    // ---- layer 2 ----
    gemm2_kernel<<<cdiv(NN, 64), 256, 0, stream>>>(z1, W2, asr2, ads2, h1, as2, ad2);
    gat2_gather<<<cdiv(NN, 4), 256, 0, stream>>>(begA, endA, csrcol, as2, ad2, h1, b2, z2);

    // ---- link-prediction logits ----
    logits_kernel<<<cdiv((long long)2 * ETEST * 16, 256), 256, 0, stream>>>(pos, neg, z2, out);
}